// Round 4
// baseline (391.403 us; speedup 1.0000x reference)
//
#include <hip/hip_runtime.h>

// RunningCenters R4: one-pass gather-partition + register-accumulated gather.
// R3 post-mortem: chain ~135us = sort pipeline ~35us + class_sum ~100us
// (2.6 TB/s gather). R4 replaces the 4-kernel sort with a single partition
// kernel: block (g,s) owns 8 classes x 1/4 of y, streams y from L2 (int4),
// compacts matching indices into LDS, writes fixed-capacity per-(class,seg)
// sub-lists. No hist/scan/scatter. class_sum: 512 thr, unroll 4, 2 rows per
// wave-load, indices staged in LDS.

constexpr int C = 1000;
constexpr int D = 128;
constexpr int G = 8;      // classes per partition block
constexpr int S = 4;      // y segments
constexpr int SCAP = 256; // capacity per (class, segment); mean 125, sd 11

// ws layout: counts4 u32[C*S] @ 0 ; list int[C*S*SCAP] @ 16384 (4 MB)

__global__ __launch_bounds__(512) void partition_kernel(
    const int* __restrict__ y, int* __restrict__ list,
    unsigned int* __restrict__ counts4, int N, int segchunk) {
  const int c0 = blockIdx.x * G;
  const int s = blockIdx.y;
  __shared__ int lidx[G][SCAP];
  __shared__ unsigned int lcnt[G];
  if (threadIdx.x < G) lcnt[threadIdx.x] = 0u;
  __syncthreads();

  const int beg = s * segchunk;            // segchunk is a multiple of 4
  const int e = min(beg + segchunk, N);
  const int nvec = (e > beg) ? ((e - beg) >> 2) : 0;
  const int4* y4 = (const int4*)(y + beg);
  for (int j = threadIdx.x; j < nvec; j += 512) {
    int4 v = y4[j];
    const int base = beg + j * 4;
#pragma unroll
    for (int u = 0; u < 4; ++u) {
      const int cv = (u == 0) ? v.x : (u == 1) ? v.y : (u == 2) ? v.z : v.w;
      const unsigned int r = (unsigned int)(cv - c0);
      if (r < (unsigned int)G) {
        unsigned int pos = atomicAdd(&lcnt[r], 1u);
        if (pos < (unsigned int)SCAP) lidx[r][pos] = base + u;
      }
    }
  }
  for (int i = beg + nvec * 4 + threadIdx.x; i < e; i += 512) {
    const int cv = y[i];
    const unsigned int r = (unsigned int)(cv - c0);
    if (r < (unsigned int)G) {
      unsigned int pos = atomicAdd(&lcnt[r], 1u);
      if (pos < (unsigned int)SCAP) lidx[r][pos] = i;
    }
  }
  __syncthreads();

#pragma unroll
  for (int r = 0; r < G; ++r) {
    const unsigned int cnt = min(lcnt[r], (unsigned int)SCAP);
    const int gbase = ((c0 + r) * S + s) * SCAP;
    for (int t = threadIdx.x; t < (int)cnt; t += 512)
      list[gbase + t] = lidx[r][t];
  }
  if (threadIdx.x < G)
    counts4[(c0 + threadIdx.x) * S + s] =
        min(lcnt[threadIdx.x], (unsigned int)SCAP);
}

// One block (8 waves) per class; stage indices in LDS, gather float4,
// 2 rows per wave-load, unroll 4 (4 KB in flight per wave).
__global__ __launch_bounds__(512) void class_sum_kernel(
    const float* __restrict__ x, const int* __restrict__ list,
    const unsigned int* __restrict__ counts4,
    const float* __restrict__ centers, const float* __restrict__ counter,
    float* __restrict__ out) {
  const int c = blockIdx.x;
  __shared__ int idx[S * SCAP];
  __shared__ unsigned int scnt[S];
  __shared__ unsigned int sbase[S + 1];
  __shared__ float4 red[8][64];

  if (threadIdx.x < S) scnt[threadIdx.x] = counts4[c * S + threadIdx.x];
  __syncthreads();
  if (threadIdx.x == 0) {
    unsigned int run = 0;
#pragma unroll
    for (int s = 0; s < S; ++s) { sbase[s] = run; run += scnt[s]; }
    sbase[S] = run;
  }
  __syncthreads();
#pragma unroll
  for (int s = 0; s < S; ++s) {
    const int cnt = (int)scnt[s];
    const int b = (int)sbase[s];
    const int gbase = (c * S + s) * SCAP;
    for (int t = threadIdx.x; t < cnt; t += 512) idx[b + t] = list[gbase + t];
  }
  __syncthreads();

  const int n = (int)sbase[S];
  const int wave = threadIdx.x >> 6;
  const int lane = threadIdx.x & 63;
  const int half = lane >> 5;  // which row of the pair
  const int d4 = lane & 31;    // float4 slot within the row

  float4 acc = make_float4(0.f, 0.f, 0.f, 0.f);
  const int npair = n >> 1;
  int q = wave;
  for (; q + 24 < npair; q += 32) {  // 8 waves x stride 8 pairs x unroll 4
#pragma unroll
    for (int u = 0; u < 4; ++u) {
      const int p = (q + 8 * u) * 2 + half;
      float4 v = ((const float4*)(x + (size_t)idx[p] * D))[d4];
      acc.x += v.x; acc.y += v.y; acc.z += v.z; acc.w += v.w;
    }
  }
  for (; q < npair; q += 8) {
    const int p = q * 2 + half;
    float4 v = ((const float4*)(x + (size_t)idx[p] * D))[d4];
    acc.x += v.x; acc.y += v.y; acc.z += v.z; acc.w += v.w;
  }
  if ((n & 1) && threadIdx.x < 32) {  // odd tail row: wave 0, half 0
    float4 v = ((const float4*)(x + (size_t)idx[n - 1] * D))[d4];
    acc.x += v.x; acc.y += v.y; acc.z += v.z; acc.w += v.w;
  }

  red[wave][lane] = acc;
  __syncthreads();
  if (threadIdx.x < 32) {
    const int l = threadIdx.x;
    float4 sum = make_float4(0.f, 0.f, 0.f, 0.f);
#pragma unroll
    for (int w = 0; w < 8; ++w) {
      float4 a = red[w][l];
      float4 b = red[w][l + 32];
      sum.x += a.x + b.x; sum.y += a.y + b.y;
      sum.z += a.z + b.z; sum.w += a.w + b.w;
    }
    float4 cen = ((const float4*)centers)[c * 32 + l];
    float4 o;
    if (n > 0) {
      const float k = counter[0];
      const float inv = 1.f / (float)n;
      const float ik = 1.f / (k + 1.f);
      o.x = (sum.x * inv + cen.x * k) * ik;
      o.y = (sum.y * inv + cen.y * k) * ik;
      o.z = (sum.z * inv + cen.z * k) * ik;
      o.w = (sum.w * inv + cen.w * k) * ik;
    } else {
      o = cen;
    }
    ((float4*)out)[c * 32 + l] = o;
  }
}

extern "C" void kernel_launch(void* const* d_in, const int* in_sizes, int n_in,
                              void* d_out, int out_size, void* d_ws, size_t ws_size,
                              hipStream_t stream) {
  const float* x       = (const float*)d_in[0];
  const int* y         = (const int*)d_in[1];
  const float* centers = (const float*)d_in[2];
  const float* counter = (const float*)d_in[3];
  float* out = (float*)d_out;
  const int N = in_sizes[1];

  unsigned int* counts4 = (unsigned int*)d_ws;
  int* list             = (int*)((char*)d_ws + 16384);

  // segment chunk rounded up to a multiple of 4 (keeps int4 alignment)
  const int segchunk = (((N + S - 1) / S) + 3) & ~3;

  partition_kernel<<<dim3(C / G, S), dim3(512), 0, stream>>>(
      y, list, counts4, N, segchunk);
  class_sum_kernel<<<dim3(C), dim3(512), 0, stream>>>(
      x, list, counts4, centers, counter, out);
}

// Round 6
// 349.561 us; speedup vs baseline: 1.1197x; 1.1197x over previous
//
#include <hip/hip_runtime.h>

// RunningCenters R6: R5 with the compile fix — __builtin_nontemporal_load
// requires a native clang vector pointer, not HIP_vector_type. Use
// ext_vector_type(4) float for the x row loads. Otherwise identical to R3
// (measured best 372.6us) + unroll 8 + nt loads in class_sum.

constexpr int C = 1000;
constexpr int D = 128;
constexpr int BS = 128;    // sort blocks
constexpr int TS = 512;    // sort threads/block
constexpr int TILE = 2048; // idx staging tile (8 KB LDS)

typedef float f4 __attribute__((ext_vector_type(4)));

// ws layout (all regions fully written before read; poison-safe, no memset):
// counts  u32[1024]    @ 0
// offsets u32[1032]    @ 4096
// hist    u32[BS*C]    @ 8192        (500 KB; becomes blockBase in-place)
// sorted  int[N]       @ 8192 + BS*C*4

__global__ __launch_bounds__(TS) void hist_kernel(
    const int* __restrict__ y, unsigned int* __restrict__ hist,
    int N, int chunk) {
  __shared__ unsigned int h[C];
  for (int t = threadIdx.x; t < C; t += TS) h[t] = 0u;
  __syncthreads();
  const int b = blockIdx.x;
  const int beg = b * chunk;
  const int e = min(beg + chunk, N);
  for (int i = beg + threadIdx.x; i < e; i += TS) atomicAdd(&h[y[i]], 1u);
  __syncthreads();
  for (int t = threadIdx.x; t < C; t += TS) hist[b * C + t] = h[t];
}

__global__ __launch_bounds__(64) void colscan_kernel(
    unsigned int* __restrict__ hist, unsigned int* __restrict__ counts) {
  const int c = blockIdx.x * 64 + threadIdx.x;
  if (c >= C) return;
  unsigned int run = 0;
  int b = 0;
  for (; b + 3 < BS; b += 4) {
    unsigned int v0 = hist[(b + 0) * C + c];
    unsigned int v1 = hist[(b + 1) * C + c];
    unsigned int v2 = hist[(b + 2) * C + c];
    unsigned int v3 = hist[(b + 3) * C + c];
    hist[(b + 0) * C + c] = run; run += v0;
    hist[(b + 1) * C + c] = run; run += v1;
    hist[(b + 2) * C + c] = run; run += v2;
    hist[(b + 3) * C + c] = run; run += v3;
  }
  for (; b < BS; ++b) {
    unsigned int v = hist[b * C + c];
    hist[b * C + c] = run;
    run += v;
  }
  counts[c] = run;
}

__global__ __launch_bounds__(1024) void scan_kernel(
    const unsigned int* __restrict__ counts,
    unsigned int* __restrict__ offsets) {
  __shared__ unsigned int buf[2][1024];
  const int t = threadIdx.x;
  unsigned int v = (t < C) ? counts[t] : 0u;
  buf[0][t] = v;
  __syncthreads();
  int s = 0;
  for (int off = 1; off < 1024; off <<= 1) {
    unsigned int u = buf[s][t];
    if (t >= off) u += buf[s][t - off];
    buf[1 - s][t] = u;
    s = 1 - s;
    __syncthreads();
  }
  if (t < C) {
    unsigned int incl = buf[s][t];
    offsets[t] = incl - v;
    if (t == C - 1) offsets[C] = incl;
  }
}

__global__ __launch_bounds__(TS) void scatter_kernel(
    const int* __restrict__ y, const unsigned int* __restrict__ hist,
    const unsigned int* __restrict__ offsets, int* __restrict__ sorted,
    int N, int chunk) {
  __shared__ unsigned int cur[C];
  const int b = blockIdx.x;
  for (int t = threadIdx.x; t < C; t += TS)
    cur[t] = offsets[t] + hist[b * C + t];
  __syncthreads();
  const int beg = b * chunk;
  const int e = min(beg + chunk, N);
  for (int i = beg + threadIdx.x; i < e; i += TS) {
    int c = y[i];
    unsigned int pos = atomicAdd(&cur[c], 1u);
    sorted[pos] = i;
  }
}

// One block (4 waves) per class. Indices staged in LDS; each wave-load
// covers 2 rows (lane>>5 picks row of pair, lane&31 picks float4 of row).
// R6: unroll 8, non-temporal x loads (native vec type).
__global__ __launch_bounds__(256) void class_sum_kernel(
    const float* __restrict__ x, const int* __restrict__ sorted,
    const unsigned int* __restrict__ offsets,
    const float* __restrict__ centers, const float* __restrict__ counter,
    float* __restrict__ out) {
  const int c = blockIdx.x;
  const int begin = (int)offsets[c];
  const int n = (int)offsets[c + 1] - begin;
  const int wave = threadIdx.x >> 6;
  const int lane = threadIdx.x & 63;
  const int half = lane >> 5;   // which row of the pair
  const int d4 = lane & 31;     // which float4 within the row

  __shared__ int idx[TILE];
  __shared__ f4 red[4][64];
  f4 acc = (f4)(0.f);

  for (int t0 = 0; t0 < n; t0 += TILE) {
    const int nt = min(TILE, n - t0);
    __syncthreads();
    for (int t = threadIdx.x; t < nt; t += 256) idx[t] = sorted[begin + t0 + t];
    __syncthreads();
    const int npair = nt >> 1;
    int q = wave;
    for (; q + 28 < npair; q += 32) {  // unroll 8: 8 x 1KB loads in flight
#pragma unroll
      for (int u = 0; u < 8; ++u) {
        const int p = (q + 4 * u) * 2 + half;
        f4 v = __builtin_nontemporal_load(
            (const f4*)(x + (size_t)idx[p] * D) + d4);
        acc += v;
      }
    }
    for (; q < npair; q += 4) {
      const int p = q * 2 + half;
      f4 v = __builtin_nontemporal_load(
          (const f4*)(x + (size_t)idx[p] * D) + d4);
      acc += v;
    }
    if ((nt & 1) && wave == 0 && half == 0) {  // odd tail point, lanes 0-31
      f4 v = __builtin_nontemporal_load(
          (const f4*)(x + (size_t)idx[nt - 1] * D) + d4);
      acc += v;
    }
  }

  red[wave][lane] = acc;
  __syncthreads();
  if (threadIdx.x < 32) {
    const int l = threadIdx.x;
    f4 s = (f4)(0.f);
#pragma unroll
    for (int w = 0; w < 4; ++w) s += red[w][l] + red[w][l + 32];
    const f4 cen = ((const f4*)centers)[c * 32 + l];
    f4 o;
    if (n > 0) {
      const float k = counter[0];
      const float inv = 1.f / (float)n;
      const float ik = 1.f / (k + 1.f);
      o = (s * inv + cen * k) * ik;
    } else {
      o = cen;
    }
    ((f4*)out)[c * 32 + l] = o;
  }
}

extern "C" void kernel_launch(void* const* d_in, const int* in_sizes, int n_in,
                              void* d_out, int out_size, void* d_ws, size_t ws_size,
                              hipStream_t stream) {
  const float* x       = (const float*)d_in[0];
  const int* y         = (const int*)d_in[1];
  const float* centers = (const float*)d_in[2];
  const float* counter = (const float*)d_in[3];
  float* out = (float*)d_out;
  const int N = in_sizes[1];

  unsigned int* counts  = (unsigned int*)d_ws;
  unsigned int* offsets = (unsigned int*)((char*)d_ws + 4096);
  unsigned int* hist    = (unsigned int*)((char*)d_ws + 8192);
  int* sorted           = (int*)((char*)d_ws + 8192 + (size_t)BS * C * 4);

  const int chunk = (N + BS - 1) / BS;

  hist_kernel<<<dim3(BS), dim3(TS), 0, stream>>>(y, hist, N, chunk);
  colscan_kernel<<<dim3(16), dim3(64), 0, stream>>>(hist, counts);
  scan_kernel<<<dim3(1), dim3(1024), 0, stream>>>(counts, offsets);
  scatter_kernel<<<dim3(BS), dim3(TS), 0, stream>>>(y, hist, offsets, sorted,
                                                    N, chunk);
  class_sum_kernel<<<dim3(C), dim3(256), 0, stream>>>(x, sorted, offsets,
                                                      centers, counter, out);
}